// Round 6
// baseline (175.721 us; speedup 1.0000x reference)
//
#include <hip/hip_runtime.h>
#include <hip/hip_fp16.h>

// Depthwise 41-tap separable gaussian blur of flow = noise*2-1.
// [16, 512, 512, 2] fp32, SAME zero padding.
//
// R6: two streaming kernels, fp16x2 intermediate (scaled by 1/S) in d_ws.
//  K_v: vertical conv, no LDS/barriers, lane-dense loads+stores, PVV=32.
//  K_h: horizontal conv, 8 full rows staged in LDS with an INJECTIVE padded
//       layout (monotone phys(x)=x+8*(x>>4); R5's additive "swizzle" collided),
//       register sliding window, direct float4 stores (each thread owns a full
//       aligned 128B line -> no cross-XCD partial-line writebacks).
#define NB   16
#define H    512
#define W    512
#define KW   41
#define HALO 20

#define PVV  32               // K_v outputs per thread (72 rows read / 32 out = 2.25x)

#define ROWS 8                // K_h rows per block
#define TLOG 552              // logical staged row: conv reads indices 0..551
#define TPHYS 825             // physical row stride (words). 825%32=25 (odd) ->
                              // 25y mod 8 distinct; + chunk pad {0,8,16,24}:
                              // conv reads hit all 32 banks x 2 lanes = free.
#define PX   16               // K_h outputs per thread (32 chunks x 16 = 512)

// Injective bank-spread: +8 words of pad per 16-word chunk (monotone).
__device__ __forceinline__ int PHYS(int x) { return x + ((x >> 4) << 3); }
// max PHYS(551) = 551 + 8*34 = 823 < 825.

// Raw gaussian taps exp(-d^2/50), d=-20..20; each pass folds in INV_S.
constexpr float G[KW] = {
  0.0003354626f, 0.0007318024f, 0.0015338104f, 0.0030887172f,
  0.0059760229f, 0.0111089965f, 0.0198410947f, 0.0340474548f,
  0.0561347628f, 0.0889216176f, 0.1353352832f, 0.1978986990f,
  0.2780373005f, 0.3753110988f, 0.4867522560f, 0.6065306597f,
  0.7261490371f, 0.8352702114f, 0.9231163464f, 0.9801986733f,
  1.0f,
  0.9801986733f, 0.9231163464f, 0.8352702114f, 0.7261490371f,
  0.6065306597f, 0.4867522560f, 0.3753110988f, 0.2780373005f,
  0.1978986990f, 0.1353352832f, 0.0889216176f, 0.0561347628f,
  0.0340474548f, 0.0198410947f, 0.0111089965f, 0.0059760229f,
  0.0030887172f, 0.0015338104f, 0.0007318024f, 0.0003354626f
};
constexpr float gsum() { float s = 0.f; for (int i = 0; i < KW; ++i) s += G[i]; return s; }
constexpr float INV_S  = 1.0f / gsum();
constexpr float INV_S2 = 1.0f / (gsum() * gsum());

// ---------------- K_v: vertical pass, noise -> mid (f16x2, x 1/S) ----------------
__global__ __launch_bounds__(256, 2)
void kv_vertical(const float* __restrict__ noise, __half2* __restrict__ mid) {
    const int tid = threadIdx.x;
    const int bx  = blockIdx.x;               // (yg<<1)|xchunk : 16*2 = 32
    const int b   = blockIdx.y;
    const int x   = (bx & 1) * 256 + tid;     // f2 column 0..511 (lane-dense)
    const int yg  = bx >> 1;                  // 0..15
    const int ysb = yg * PVV - HALO;
    const float* __restrict__ colp = noise + ((size_t)b * (H * W) + x) * 2;

    float2 acc[PVV];
    #pragma unroll
    for (int p = 0; p < PVV; ++p) acc[p] = make_float2(0.f, 0.f);

    #pragma unroll
    for (int j = 0; j < PVV + KW - 1; ++j) {            // 72 rows
        const int ys = ysb + j;
        const int cy = min(max(ys, 0), H - 1);          // clamped -> always legal
        const float a  = (ys == cy) ? 2.0f : 0.0f;      // zero-pad + transform select
        const float bb = (ys == cy) ? -1.0f : 0.0f;
        const float2 u = *(const float2*)(colp + (size_t)cy * (W * 2));
        float2 v;
        v.x = __builtin_fmaf(u.x, a, bb);
        v.y = __builtin_fmaf(u.y, a, bb);
        #pragma unroll
        for (int p = 0; p < PVV; ++p) {
            const int t = j - p;                        // compile-time after unroll
            if (t >= 0 && t < KW) {
                acc[p].x = __builtin_fmaf(G[t], v.x, acc[p].x);
                acc[p].y = __builtin_fmaf(G[t], v.y, acc[p].y);
            }
        }
    }
    __half2* __restrict__ mb = mid + (size_t)b * (H * W) + x;
    #pragma unroll
    for (int p = 0; p < PVV; ++p) {                     // lane-dense b32 stores
        float2 r;
        r.x = acc[p].x * INV_S;                         // |r| <= 1: fp16-safe
        r.y = acc[p].y * INV_S;
        mb[(size_t)(yg * PVV + p) * W] = __float22half2_rn(r);
    }
}

// ---------------- K_h: horizontal pass, mid -> out ----------------
__global__ __launch_bounds__(256, 4)
void kh_horizontal(const __half2* __restrict__ mid, float* __restrict__ out) {
    __shared__ __half2 tile[ROWS * TPHYS];   // 8*825*4 = 26400 B -> 4+ blocks/CU

    const int tid = threadIdx.x;
    const int rb  = blockIdx.x;              // row band 0..63
    const int b   = blockIdx.y;
    const int y0  = rb * ROWS;
    const __half2* __restrict__ mb = mid + (size_t)b * (H * W) + (size_t)y0 * W;

    // stage 8 zero-padded rows; lanes consecutive -> dense b32 global loads,
    // LDS writes land 2-way max (16-chunks + 8-pad).
    for (int i = tid; i < ROWS * TLOG; i += 256) {
        const int r  = i / TLOG;
        const int cc = i - r * TLOG;
        const int xs = cc - HALO;
        __half2 v = __float2half2_rn(0.0f);
        if ((unsigned)xs < (unsigned)W) v = mb[r * W + xs];
        tile[r * TPHYS + PHYS(cc)] = v;
    }
    __syncthreads();

    // sliding-window conv: thread = (row y=tid&7, chunk xg=tid>>3), 16 outputs.
    // Read banks: 25y (distinct mod 8) + 24xg ({0,8,16,24}) -> 32 banks, 2-way.
    const int y  = tid & 7;
    const int xg = tid >> 3;                 // 0..31
    const int x0 = xg * PX;
    float2 acc[PX];
    #pragma unroll
    for (int p = 0; p < PX; ++p) acc[p] = make_float2(0.f, 0.f);

    const __half2* __restrict__ trow = tile + y * TPHYS;
    #pragma unroll
    for (int j = 0; j < PX + KW - 1; ++j) {             // 56 b32 LDS reads
        const float2 v = __half22float2(trow[PHYS(x0 + j)]);
        #pragma unroll
        for (int p = 0; p < PX; ++p) {
            const int t = j - p;
            if (t >= 0 && t < KW) {
                acc[p].x = __builtin_fmaf(G[t], v.x, acc[p].x);
                acc[p].y = __builtin_fmaf(G[t], v.y, acc[p].y);
            }
        }
    }

    // direct stores: thread owns f2 [x0, x0+16) of row y0+y = one aligned 128B
    // line; 8 float4 stores, L2 merges (block owns full 4KB rows -> no
    // cross-XCD partial lines).
    float2* __restrict__ orow = (float2*)out + ((size_t)b * H + y0 + y) * W;
    #pragma unroll
    for (int q = 0; q < PX / 2; ++q) {
        float4 r;
        r.x = acc[2*q].x   * INV_S;
        r.y = acc[2*q].y   * INV_S;
        r.z = acc[2*q+1].x * INV_S;
        r.w = acc[2*q+1].y * INV_S;
        *(float4*)&orow[x0 + 2*q] = r;
    }
}

// ---------------- fallback: R4 fused kernel (if ws too small) ----------------
#define TXF   88
#define TYF   32
#define PVVF  16
#define PXF   11
#define MSTR  129
#define OSTR  89
#define SMEM_F2 (TYF * MSTR)

__global__ __launch_bounds__(256, 4)
void randflow_fused(const float* __restrict__ noise, float* __restrict__ out) {
    __shared__ float2 smem[SMEM_F2];
    const int tid = threadIdx.x;
    const int bx  = blockIdx.x;
    const int tx0 = bx * TXF;
    const int ty0 = blockIdx.y * TYF;
    const int b   = blockIdx.z;
    const float* __restrict__ src = noise + (size_t)b * (H * W * 2);
    {
        const int sx  = tid & 127;
        const int yg  = tid >> 7;
        const int gx  = tx0 + sx - HALO;
        const int cgx = min(max(gx, 0), W - 1);
        const float sa = (gx == cgx) ? 2.0f : 0.0f;
        const float sb = (gx == cgx) ? -1.0f : 0.0f;
        const int  ysb = ty0 + yg * PVVF - HALO;
        const float* __restrict__ colp = src + 2 * cgx;
        float2 acc[PVVF];
        #pragma unroll
        for (int p = 0; p < PVVF; ++p) acc[p] = make_float2(0.f, 0.f);
        #pragma unroll
        for (int j = 0; j < PVVF + KW - 1; ++j) {
            const int ys = ysb + j;
            const int cy = min(max(ys, 0), H - 1);
            const float a  = (ys == cy) ? sa : 0.0f;
            const float bb = (ys == cy) ? sb : 0.0f;
            const float2 u = *(const float2*)(colp + (size_t)cy * (W * 2));
            float2 v;
            v.x = __builtin_fmaf(u.x, a, bb);
            v.y = __builtin_fmaf(u.y, a, bb);
            #pragma unroll
            for (int p = 0; p < PVVF; ++p) {
                const int t = j - p;
                if (t >= 0 && t < KW) {
                    acc[p].x = __builtin_fmaf(G[t], v.x, acc[p].x);
                    acc[p].y = __builtin_fmaf(G[t], v.y, acc[p].y);
                }
            }
        }
        #pragma unroll
        for (int p = 0; p < PVVF; ++p)
            smem[(yg * PVVF + p) * MSTR + sx] = acc[p];
    }
    __syncthreads();
    const int y  = tid & 31;
    const int xg = tid >> 5;
    const int x0 = xg * PXF;
    float2 facc[PXF];
    {
        #pragma unroll
        for (int p = 0; p < PXF; ++p) facc[p] = make_float2(0.f, 0.f);
        #pragma unroll
        for (int j = 0; j < PXF + KW - 1; ++j) {
            const float2 v = smem[y * MSTR + x0 + j];
            #pragma unroll
            for (int p = 0; p < PXF; ++p) {
                const int t = j - p;
                if (t >= 0 && t < KW) {
                    facc[p].x = __builtin_fmaf(G[t], v.x, facc[p].x);
                    facc[p].y = __builtin_fmaf(G[t], v.y, facc[p].y);
                }
            }
        }
    }
    __syncthreads();
    #pragma unroll
    for (int p = 0; p < PXF; ++p) {
        float2 r;
        r.x = facc[p].x * INV_S2;
        r.y = facc[p].y * INV_S2;
        smem[y * OSTR + x0 + p] = r;
    }
    __syncthreads();
    #pragma unroll
    for (int p = 0; p < PXF; ++p) {
        const int flat = p * 256 + tid;
        const int ry = flat / TXF;
        const int rx = flat - ry * TXF;
        const int xo = tx0 + rx;
        if (xo < W) {
            const int yo = ty0 + ry;
            *(float2*)(out + (((size_t)b * H + yo) * W + xo) * 2) = smem[ry * OSTR + rx];
        }
    }
}

extern "C" void kernel_launch(void* const* d_in, const int* in_sizes, int n_in,
                              void* d_out, int out_size, void* d_ws, size_t ws_size,
                              hipStream_t stream) {
    // d_in[0] = inputs [16,512,512,1]  -- UNUSED by the reference
    // d_in[1] = rand_noise [16,512,512,2] fp32
    const float* noise = (const float*)d_in[1];
    float* out = (float*)d_out;

    const size_t mid_bytes = (size_t)NB * H * W * sizeof(__half2);   // 16.78 MB
    if (ws_size >= mid_bytes) {
        __half2* mid = (__half2*)d_ws;
        dim3 gv(32, NB);             // (16 ygroups x 2 xchunks) x batch = 512 blocks
        kv_vertical<<<gv, dim3(256), 0, stream>>>(noise, mid);
        dim3 gh(H / ROWS, NB);       // 64 x 16 = 1024 blocks
        kh_horizontal<<<gh, dim3(256), 0, stream>>>(mid, out);
    } else {
        dim3 gf((W + TXF - 1) / TXF, H / TYF, NB);
        randflow_fused<<<gf, dim3(256), 0, stream>>>(noise, out);
    }
}

// Round 7
// 152.118 us; speedup vs baseline: 1.1552x; 1.1552x over previous
//
#include <hip/hip_runtime.h>

// Depthwise 41-tap separable gaussian blur of flow = noise*2-1.
// [16, 512, 512, 2] fp32, SAME zero padding.
//
// R7: single fused kernel, full-row bands. Block = 8 output rows x 512 pixels.
//  Phase 1: vertical conv straight from global (16B/lane dense float4 loads,
//           48 input rows, clamped addresses + select for zero-pad), results
//           (f32) to LDS rows with ds_write_b128. x-halo (20 px each side)
//           zero-filled. ONE barrier.
//  Phase 2: horizontal conv from LDS: thread = pixel pair, 21 dense
//           ds_read_b128 per row, 164 FMA, one lane-dense
//           global_store_dwordx4 per row (thread owns 16B of a full 4KB row
//           -> no partial-line write amplification).
// All f32 (no fp16 mid). No workspace. Unroll scale kept <= R4's proven size
// (R6 lesson: 72x64 unroll made the compiler demote acc[] to scratch).
#define NB   16
#define H    512
#define W    512
#define KW   41
#define HALO 20

#define TYB  8               // output rows per band
#define NROW (TYB + KW - 1)  // 48 input rows read per band
#define MIDW 552             // f2 per LDS row: 20 zero + 512 + 20 zero
#define MSTR 554             // row stride in f2 (4432 B, 16B aligned)

// Raw gaussian taps exp(-d^2/50), d=-20..20; (1/sum)^2 folded at the store.
constexpr float G[KW] = {
  0.0003354626f, 0.0007318024f, 0.0015338104f, 0.0030887172f,
  0.0059760229f, 0.0111089965f, 0.0198410947f, 0.0340474548f,
  0.0561347628f, 0.0889216176f, 0.1353352832f, 0.1978986990f,
  0.2780373005f, 0.3753110988f, 0.4867522560f, 0.6065306597f,
  0.7261490371f, 0.8352702114f, 0.9231163464f, 0.9801986733f,
  1.0f,
  0.9801986733f, 0.9231163464f, 0.8352702114f, 0.7261490371f,
  0.6065306597f, 0.4867522560f, 0.3753110988f, 0.2780373005f,
  0.1978986990f, 0.1353352832f, 0.0889216176f, 0.0561347628f,
  0.0340474548f, 0.0198410947f, 0.0111089965f, 0.0059760229f,
  0.0030887172f, 0.0015338104f, 0.0007318024f, 0.0003354626f
};
constexpr float gsum() { float s = 0.f; for (int i = 0; i < KW; ++i) s += G[i]; return s; }
constexpr float INV_S2 = 1.0f / (gsum() * gsum());

__global__ __launch_bounds__(256, 4)
void randflow_band(const float* __restrict__ noise, float* __restrict__ out) {
    // mid[r][i]: horizontal-conv input, i = pixel + HALO. 8*554*8 = 35456 B
    // -> 4 blocks/CU (142 KB), 16 waves/CU; grid = exactly one round.
    __shared__ float2 mid[TYB * MSTR];

    const int tid = threadIdx.x;
    const int rb  = blockIdx.x;           // band 0..63
    const int b   = blockIdx.y;
    const int y0  = rb * TYB;

    // ---- phase 1: vertical conv, global -> LDS (f32) -------------------
    {
        // thread = f4 column c: pixels {2c, 2c+1}, both channels. 16B/lane dense.
        const int c = tid;                               // 0..255
        const float* __restrict__ colp = noise + (size_t)b * (H * W * 2) + 4 * c;

        float4 acc[TYB];
        #pragma unroll
        for (int p = 0; p < TYB; ++p) acc[p] = make_float4(0.f, 0.f, 0.f, 0.f);

        #pragma unroll
        for (int j = 0; j < NROW; ++j) {                 // 48 rows
            const int ys = y0 - HALO + j;
            const int cy = min(max(ys, 0), H - 1);       // clamped -> always legal
            const float a  = (ys == cy) ? 2.0f : 0.0f;   // zero-pad + 2u-1 select
            const float bb = (ys == cy) ? -1.0f : 0.0f;
            const float4 u = *(const float4*)(colp + (size_t)cy * (W * 2));
            float4 v;
            v.x = __builtin_fmaf(u.x, a, bb);
            v.y = __builtin_fmaf(u.y, a, bb);
            v.z = __builtin_fmaf(u.z, a, bb);
            v.w = __builtin_fmaf(u.w, a, bb);
            #pragma unroll
            for (int p = 0; p < TYB; ++p) {
                const int t = j - p;                     // compile-time after unroll
                if (t >= 0 && t < KW) {
                    acc[p].x = __builtin_fmaf(G[t], v.x, acc[p].x);
                    acc[p].y = __builtin_fmaf(G[t], v.y, acc[p].y);
                    acc[p].z = __builtin_fmaf(G[t], v.z, acc[p].z);
                    acc[p].w = __builtin_fmaf(G[t], v.w, acc[p].w);
                }
            }
        }
        // mid rows: pixel pair {2c,2c+1} -> buffer f2 idx 2c+HALO (byte 16c+160,
        // 16B aligned) -> ds_write_b128, lanes dense.
        #pragma unroll
        for (int p = 0; p < TYB; ++p)
            *(float4*)&mid[p * MSTR + 2 * c + HALO] = acc[p];
    }
    // zero the x-halo: f2 idx [0,20) and [532,552) per row = 320 entries.
    for (int i = tid; i < TYB * 2 * HALO; i += 256) {
        const int r = i / (2 * HALO);
        const int k = i - r * (2 * HALO);
        const int f2i = (k < HALO) ? k : (k + W);        // 0..19 or 532..551
        mid[r * MSTR + f2i] = make_float2(0.f, 0.f);
    }
    __syncthreads();

    // ---- phase 2: horizontal conv, LDS -> global -----------------------
    // thread = pixel-pair xp: outputs {2xp, 2xp+1}, rows 0..7.
    // Window buffer f2 idx [2xp, 2xp+42) = 21 b128 reads (16B/lane dense).
    {
        const int xp = tid;                              // 0..255
        float* __restrict__ obase =
            out + (((size_t)b * H + y0) * W + 2 * xp) * 2;

        #pragma unroll
        for (int r = 0; r < TYB; ++r) {
            const float2* __restrict__ wrow = &mid[r * MSTR + 2 * xp];
            float4 o = make_float4(0.f, 0.f, 0.f, 0.f); // A.c0 A.c1 B.c0 B.c1
            #pragma unroll
            for (int k = 0; k <= 20; ++k) {              // 21 reads
                const float4 w = *(const float4*)&wrow[2 * k];
                // pixel P = 2xp-20+2k (w.xy), P+1 (w.zw)
                // outA (pixel 2xp): taps 2k, 2k+1 ; outB (2xp+1): taps 2k-1, 2k
                o.x = __builtin_fmaf(G[2 * k], w.x, o.x);
                o.y = __builtin_fmaf(G[2 * k], w.y, o.y);
                if (2 * k + 1 < KW) {
                    o.x = __builtin_fmaf(G[2 * k + 1], w.z, o.x);
                    o.y = __builtin_fmaf(G[2 * k + 1], w.w, o.y);
                }
                if (2 * k - 1 >= 0) {
                    o.z = __builtin_fmaf(G[2 * k - 1], w.x, o.z);
                    o.w = __builtin_fmaf(G[2 * k - 1], w.y, o.w);
                }
                o.z = __builtin_fmaf(G[2 * k], w.z, o.z);
                o.w = __builtin_fmaf(G[2 * k], w.w, o.w);
            }
            float4 s;
            s.x = o.x * INV_S2;
            s.y = o.y * INV_S2;
            s.z = o.z * INV_S2;
            s.w = o.w * INV_S2;
            *(float4*)(obase + (size_t)r * (W * 2)) = s; // lane-dense dwordx4
        }
    }
}

extern "C" void kernel_launch(void* const* d_in, const int* in_sizes, int n_in,
                              void* d_out, int out_size, void* d_ws, size_t ws_size,
                              hipStream_t stream) {
    // d_in[0] = inputs [16,512,512,1]  -- UNUSED by the reference
    // d_in[1] = rand_noise [16,512,512,2] fp32
    const float* noise = (const float*)d_in[1];
    float* out = (float*)d_out;

    dim3 grid(H / TYB, NB);     // 64 bands x 16 batches = 1024 blocks
    randflow_band<<<grid, dim3(256), 0, stream>>>(noise, out);
}

// Round 8
// 135.240 us; speedup vs baseline: 1.2993x; 1.1248x over previous
//
#include <hip/hip_runtime.h>

// Depthwise 41-tap separable gaussian blur of flow = noise*2-1.
// [16, 512, 512, 2] fp32, SAME zero padding.
//
// R8: fused full-row band kernel (8 output rows x 512 px per block).
//  Phase 1: vertical conv from global (dense float4 loads, clamped addrs +
//           select for zero-pad) -> LDS rows (f32, ds_write_b128). One barrier.
//  Phase 2: horizontal conv: thread = (row, 8-px chunk) x 2 items, 24
//           ds_read_b128 per item (bank-exact tiling), 656 FMA, 4 dense
//           float4 stores per item (full 128B lines, one writer per line).
//  R7 post-mortem: FETCH/WRITE both +104 MiB == scratch spill round-trip from
//  the fat unrolled phase 2; this phase 2 is register-lean (item loop rolled).
//  XCD swizzle: contiguous bands per XCD so y-halos dedupe in one L2.
#define NB   16
#define H    512
#define W    512
#define KW   41
#define HALO 20

#define TYB  8               // output rows per band
#define NROW (TYB + KW - 1)  // 48 input rows read per band
#define MSTR 562             // LDS row stride in f2: 2*562 = 1124 = 4 (mod 32)
                             // -> b128 lane patterns tile 32 banks exactly.
                             // row = 20 zero + 512 + 20 zero = 552 used f2.

// Raw gaussian taps exp(-d^2/50), d=-20..20; (1/sum)^2 folded at the store.
constexpr float G[KW] = {
  0.0003354626f, 0.0007318024f, 0.0015338104f, 0.0030887172f,
  0.0059760229f, 0.0111089965f, 0.0198410947f, 0.0340474548f,
  0.0561347628f, 0.0889216176f, 0.1353352832f, 0.1978986990f,
  0.2780373005f, 0.3753110988f, 0.4867522560f, 0.6065306597f,
  0.7261490371f, 0.8352702114f, 0.9231163464f, 0.9801986733f,
  1.0f,
  0.9801986733f, 0.9231163464f, 0.8352702114f, 0.7261490371f,
  0.6065306597f, 0.4867522560f, 0.3753110988f, 0.2780373005f,
  0.1978986990f, 0.1353352832f, 0.0889216176f, 0.0561347628f,
  0.0340474548f, 0.0198410947f, 0.0111089965f, 0.0059760229f,
  0.0030887172f, 0.0015338104f, 0.0007318024f, 0.0003354626f
};
constexpr float gsum() { float s = 0.f; for (int i = 0; i < KW; ++i) s += G[i]; return s; }
constexpr float INV_S2 = 1.0f / (gsum() * gsum());

__global__ __launch_bounds__(256, 4)
void randflow_band(const float* __restrict__ noise, float* __restrict__ out) {
    // 8 * 562 * 8 B = 35968 B -> 4 blocks/CU (143.9 KB), 16 waves/CU.
    __shared__ float2 mid[TYB * MSTR];

    const int tid = threadIdx.x;
    // XCD-contiguous band swizzle: XCD x gets bands g in [x*128,(x+1)*128) ->
    // co-resident blocks on one XCD have adjacent bands; 40-row halo overlap
    // stays in that XCD's 4 MiB L2 (working set ~3 MB).
    const int n  = blockIdx.x;                 // 0..1023
    const int g  = (n & 7) * 128 + (n >> 3);
    const int rb = g & 63;                     // band
    const int b  = g >> 6;                     // batch
    const int y0 = rb * TYB;

    // ---- phase 1: vertical conv, global -> LDS (f32) -------------------
    {
        // thread = f4 column c: pixels {2c, 2c+1}, both channels; 16B/lane dense.
        const int c = tid;                               // 0..255
        const float* __restrict__ colp = noise + (size_t)b * (H * W * 2) + 4 * c;

        float4 acc[TYB];
        #pragma unroll
        for (int p = 0; p < TYB; ++p) acc[p] = make_float4(0.f, 0.f, 0.f, 0.f);

        #pragma unroll
        for (int j = 0; j < NROW; ++j) {                 // 48 rows
            const int ys = y0 - HALO + j;
            const int cy = min(max(ys, 0), H - 1);       // clamped -> always legal
            const float a  = (ys == cy) ? 2.0f : 0.0f;   // zero-pad + 2u-1 select
            const float bb = (ys == cy) ? -1.0f : 0.0f;
            const float4 u = *(const float4*)(colp + (size_t)cy * (W * 2));
            float4 v;
            v.x = __builtin_fmaf(u.x, a, bb);
            v.y = __builtin_fmaf(u.y, a, bb);
            v.z = __builtin_fmaf(u.z, a, bb);
            v.w = __builtin_fmaf(u.w, a, bb);
            #pragma unroll
            for (int p = 0; p < TYB; ++p) {
                const int t = j - p;                     // compile-time after unroll
                if (t >= 0 && t < KW) {
                    acc[p].x = __builtin_fmaf(G[t], v.x, acc[p].x);
                    acc[p].y = __builtin_fmaf(G[t], v.y, acc[p].y);
                    acc[p].z = __builtin_fmaf(G[t], v.z, acc[p].z);
                    acc[p].w = __builtin_fmaf(G[t], v.w, acc[p].w);
                }
            }
        }
        // f2 idx 2c+HALO: byte = p*4496 + 16c + 160, 16B aligned, lanes tile banks.
        #pragma unroll
        for (int p = 0; p < TYB; ++p)
            *(float4*)&mid[p * MSTR + 2 * c + HALO] = acc[p];
    }
    // zero the x-halo: f2 idx [0,20) and [532,552) per row = 320 entries.
    for (int i = tid; i < TYB * 2 * HALO; i += 256) {
        const int r = i / (2 * HALO);
        const int k = i - r * (2 * HALO);
        const int f2i = (k < HALO) ? k : (k + W);        // 0..19 or 532..551
        mid[r * MSTR + f2i] = make_float2(0.f, 0.f);
    }
    __syncthreads();

    // ---- phase 2: horizontal conv, LDS -> global -----------------------
    // item = (row r, 8-px chunk ck); 512 items, 2 per thread (loop NOT
    // unrolled -> small code, low reg pressure). Window: px [ck*8-20,
    // ck*8+27] = buf f2 [ck*8, ck*8+48) = 24 b128 reads, bank-exact.
    #pragma unroll 1
    for (int it = 0; it < 2; ++it) {
        const int id = tid + 256 * it;
        const int r  = id & 7;
        const int ck = id >> 3;                          // 0..63
        const float2* __restrict__ wrow = &mid[r * MSTR + ck * 8];

        float2 acc[8];
        #pragma unroll
        for (int p = 0; p < 8; ++p) acc[p] = make_float2(0.f, 0.f);

        #pragma unroll
        for (int k = 0; k < 24; ++k) {                   // 24 b128 reads
            const float4 w = *(const float4*)&wrow[2 * k];
            // w.xy = px (ck*8 + 2k - 20) -> tap t0 = 2k - p for output px ck*8+p
            // w.zw = next px            -> tap t0 + 1
            #pragma unroll
            for (int p = 0; p < 8; ++p) {
                const int t0 = 2 * k - p;
                if (t0 >= 0 && t0 < KW) {
                    acc[p].x = __builtin_fmaf(G[t0], w.x, acc[p].x);
                    acc[p].y = __builtin_fmaf(G[t0], w.y, acc[p].y);
                }
                const int t1 = 2 * k + 1 - p;
                if (t1 >= 0 && t1 < KW) {
                    acc[p].x = __builtin_fmaf(G[t1], w.z, acc[p].x);
                    acc[p].y = __builtin_fmaf(G[t1], w.w, acc[p].y);
                }
            }
        }
        // 8 px = 64 B: 4 dense float4 stores; block owns full 4KB rows ->
        // every 128B line has exactly one writer.
        float* __restrict__ op = out + (((size_t)b * H + y0 + r) * W + ck * 8) * 2;
        #pragma unroll
        for (int q = 0; q < 4; ++q) {
            float4 s;
            s.x = acc[2 * q].x     * INV_S2;
            s.y = acc[2 * q].y     * INV_S2;
            s.z = acc[2 * q + 1].x * INV_S2;
            s.w = acc[2 * q + 1].y * INV_S2;
            *(float4*)(op + 4 * q) = s;
        }
    }
}

extern "C" void kernel_launch(void* const* d_in, const int* in_sizes, int n_in,
                              void* d_out, int out_size, void* d_ws, size_t ws_size,
                              hipStream_t stream) {
    // d_in[0] = inputs [16,512,512,1]  -- UNUSED by the reference
    // d_in[1] = rand_noise [16,512,512,2] fp32
    const float* noise = (const float*)d_in[1];
    float* out = (float*)d_out;

    randflow_band<<<dim3(64 * NB), dim3(256), 0, stream>>>(noise, out);
}